// Round 11
// baseline (220.308 us; speedup 1.0000x reference)
//
#include <hip/hip_runtime.h>
#include <math.h>

#define BATCH 64
#define CD 256
#define NX 784
#define TRIU_N 32896
#define MSZ 65536           // elems per swizzled 256x256 matrix
#define REG_STRIDE 1032     // 128 rows * 8 elems + 8 pad (bank-conflict break)
#define ARR_STRIDE 4128     // 4 regions
#define BUF_STRIDE 16512    // 4 arrays (Ahi,Alo,Bhi,Blo) = 33KB per stage buffer

typedef unsigned short ushort_t;
typedef unsigned int uint_t;
typedef __attribute__((ext_vector_type(8))) short short8;
typedef __attribute__((ext_vector_type(16))) float floatx16;

// XCD co-location (perf heuristic only; correctness is mapping-independent).
__device__ __forceinline__ void decode_bid(int bid, int& tile, int& bb) {
    int xcd = bid & 7, g = bid >> 3;
    tile = g & 3;
    bb = ((g >> 2) << 3) | xcd;
}

__device__ __forceinline__ float bf2f(ushort_t h) {
    return __uint_as_float(((uint_t)h) << 16);
}
__device__ __forceinline__ void pack2(float f0, float f1, uint_t& hp, uint_t& lp) {
    uint_t h, l;
    asm("v_cvt_pk_bf16_f32 %0, %1, %2" : "=v"(h) : "v"(f0), "v"(f1));
    float r0 = f0 - __uint_as_float(h << 16);
    float r1 = f1 - __uint_as_float(h & 0xffff0000u);
    asm("v_cvt_pk_bf16_f32 %0, %1, %2" : "=v"(l) : "v"(r0), "v"(r1));
    hp = h; lp = l;
}
// Plain (compiler-tracked) stores: __syncthreads auto-drains them, and the
// release RMW in gbar flushes this XCD's dirty L2 (buffer_wbl2) before the
// flag becomes visible. No inline-asm stores -- round-9/10 lesson: asm
// stores are invisible to waitcnt insertion and to the memory legalizer.
__device__ __forceinline__ void store8(ushort_t* H, ushort_t* L, const float* y) {
    uint_t hw[4], lw[4];
    #pragma unroll
    for (int i = 0; i < 4; ++i) pack2(y[2*i], y[2*i+1], hw[i], lw[i]);
    *(uint4*)H = make_uint4(hw[0], hw[1], hw[2], hw[3]);
    *(uint4*)L = make_uint4(lw[0], lw[1], lw[2], lw[3]);
}

// swizzled offset of element (r,c) within one 256x256 matrix
__device__ __forceinline__ int swoff(int r, int c) {
    int p = r >> 7, s = (c >> 5) & 7, ks = (c >> 4) & 1, kh = (c >> 3) & 1;
    return ((((p * 8 + s) * 2 + ks) * 2 + kh) * 128 + (r & 127)) * 8 + (c & 7);
}

// raw workgroup barrier (no compiler vmcnt(0) drain); caller must wait first.
__device__ __forceinline__ void rawbar() {
    __builtin_amdgcn_s_barrier();
    __builtin_amdgcn_sched_barrier(0);
}

// Per-batch device barrier (4 participant blocks).
// Producer: __syncthreads (drains all tracked stores), then tid0 publishes
// with a RELEASE RMW at agent scope -- the memory legalizer emits
// s_waitcnt + buffer_wbl2 (flush this XCD's dirty L2, incl. all waves'
// phase-output stores: same CU -> same XCD L2) before the atomic.
// Consumer: relaxed poll + ACQUIRE fence (buffer_inv: L1+L2 invalidate) ->
// subsequent plain loads read fresh data from L3. Same cache-op sequence
// round 1's __threadfence barrier used (proven correct cross-XCD), minus
// redundancy. Monotonic counters, memset per launch. All 256 blocks are
// co-resident (grid == #CUs, 1 block/CU, 132KB LDS) -> spin cannot deadlock.
__device__ __forceinline__ void gbar(unsigned* bars, int slot) {
    __syncthreads();
    if (threadIdx.x == 0) {
        __hip_atomic_fetch_add(&bars[slot], 1u, __ATOMIC_RELEASE, __HIP_MEMORY_SCOPE_AGENT);
        while (__hip_atomic_load(&bars[slot], __ATOMIC_RELAXED, __HIP_MEMORY_SCOPE_AGENT) < 4u)
            __builtin_amdgcn_s_sleep(4);
        __builtin_amdgcn_fence(__ATOMIC_ACQUIRE, "agent");
    }
    __syncthreads();
    __builtin_amdgcn_sched_barrier(0);
}

// ---------------------------------------------------------------------------
// One BK=32 stage from LDS: wave computes 2 quadrants (wr, wcp*2+{0,1}).
__device__ __forceinline__ void mfma_stage8(const ushort_t* us, int bufbase,
                                            int wr, int wcp, int khalf, int lrow,
                                            floatx16* acc) {
    __builtin_amdgcn_s_setprio(1);
    #pragma unroll
    for (int ks = 0; ks < 2; ++ks) {
        const int rid = ks * 2 + khalf;
        const ushort_t* rb = us + bufbase + rid * REG_STRIDE + lrow * 8;
        short8 aH = *(const short8*)(rb + wr * 256);
        short8 aL = *(const short8*)(rb + ARR_STRIDE + wr * 256);
        #pragma unroll
        for (int cq = 0; cq < 2; ++cq) {
            const int col = wcp * 2 + cq;
            short8 bH = *(const short8*)(rb + 2 * ARR_STRIDE + col * 256);
            short8 bL = *(const short8*)(rb + 3 * ARR_STRIDE + col * 256);
            acc[cq] = __builtin_amdgcn_mfma_f32_32x32x16_bf16(aH, bH, acc[cq], 0, 0, 0);
            acc[cq] = __builtin_amdgcn_mfma_f32_32x32x16_bf16(aH, bL, acc[cq], 0, 0, 0);
            acc[cq] = __builtin_amdgcn_mfma_f32_32x32x16_bf16(aL, bH, acc[cq], 0, 0, 0);
        }
    }
    __builtin_amdgcn_s_setprio(0);
}

// accumulator -> fsmem bounce (stride 129 -> conflict-free)
__device__ __forceinline__ void acc_bounce(float* fsmem, const floatx16* acc,
                                           int wr, int wcp, int khalf, int lrow) {
    __syncthreads();
    #pragma unroll
    for (int cq = 0; cq < 2; ++cq)
        #pragma unroll
        for (int i = 0; i < 16; ++i) {
            int rl = (i & 3) + ((i >> 2) << 3) + (khalf << 2);
            fsmem[(wr * 32 + rl) * 129 + (wcp * 2 + cq) * 32 + lrow] = acc[cq][i];
        }
    __syncthreads();
}

// ---------------------------------------------------------------------------
// Gram helpers: named-register double buffer (static indexing, rule #20)
struct Cur { float4 v[2][2]; };

__device__ __forceinline__ void gr_load(const float* Xb, int rowBase, int colBase, int s,
                                        const int* side, const int* srow, const int* skq,
                                        Cur& c) {
    #pragma unroll
    for (int q = 0; q < 2; ++q) {
        int gk = s * 32 + skq[q] * 8;
        if (gk < NX) {
            const float* p = Xb + (size_t)((side[q] ? colBase : rowBase) + srow[q]) * NX + gk;
            c.v[q][0] = *(const float4*)p;
            c.v[q][1] = *(const float4*)(p + 4);
        } else {
            c.v[q][0] = make_float4(0.f, 0.f, 0.f, 0.f);
            c.v[q][1] = make_float4(0.f, 0.f, 0.f, 0.f);
        }
    }
}

__device__ __forceinline__ void gr_conv(ushort_t* us, int bufbase, const Cur& c,
                                        const int* side, const int* srow, const int* skq,
                                        float* rs) {
    #pragma unroll
    for (int q = 0; q < 2; ++q) {
        float f[8] = {c.v[q][0].x, c.v[q][0].y, c.v[q][0].z, c.v[q][0].w,
                      c.v[q][1].x, c.v[q][1].y, c.v[q][1].z, c.v[q][1].w};
        rs[q] += ((f[0] + f[1]) + (f[2] + f[3])) + ((f[4] + f[5]) + (f[6] + f[7]));
        uint_t hp[4], lp[4];
        #pragma unroll
        for (int i = 0; i < 4; ++i) pack2(f[2*i], f[2*i+1], hp[i], lp[i]);
        int base = bufbase + (side[q] * 2) * ARR_STRIDE + skq[q] * REG_STRIDE + srow[q] * 8;
        *(uint4*)(us + base)              = make_uint4(hp[0], hp[1], hp[2], hp[3]);
        *(uint4*)(us + base + ARR_STRIDE) = make_uint4(lp[0], lp[1], lp[2], lp[3]);
    }
}

// ---------------------------------------------------------------------------
// Gram phase (round-5 proven structure): Sigma = X X^T/n - m m^T, means +
// trace fused. means are block-local -> plain stores, tracked waits.
__device__ __forceinline__ void gram_phase(float* fsmem, const float* __restrict__ X,
                                           float* __restrict__ means, float* __restrict__ tr,
                                           ushort_t* __restrict__ Gh, ushort_t* __restrict__ Gl,
                                           int tile, int bb) {
    ushort_t* us = (ushort_t*)fsmem;
    float* dsh = fsmem + 16512;            // scratch beyond gram's 66KB window
    const int rowBase = (tile >> 1) * 128, colBase = (tile & 1) * 128;
    const int tid = threadIdx.x, lane = tid & 63, wv = tid >> 6;
    const int wr = wv >> 1, wcp = wv & 1;
    const int khalf = lane >> 5, lrow = lane & 31;
    const float* Xb = X + (size_t)bb * CD * NX;

    floatx16 acc[2];
    #pragma unroll
    for (int cq = 0; cq < 2; ++cq)
        #pragma unroll
        for (int i = 0; i < 16; ++i) acc[cq][i] = 0.f;

    int side[2], srow[2], skq[2];
    #pragma unroll
    for (int q = 0; q < 2; ++q) {
        int gid = q * 512 + tid;
        side[q] = gid >> 9;
        srow[q] = (gid >> 2) & 127;
        skq[q]  = gid & 3;
    }
    float rs[2] = {0.f, 0.f};

    Cur curA, curB;
    gr_load(Xb, rowBase, colBase, 0, side, srow, skq, curA);
    gr_load(Xb, rowBase, colBase, 1, side, srow, skq, curB);
    gr_conv(us, 0, curA, side, srow, skq, rs);          // stage 0 -> buf0

    for (int s = 0; s < 25; s += 2) {
        asm volatile("s_waitcnt lgkmcnt(0)" ::: "memory");
        rawbar();
        if (s + 2 <= 24) gr_load(Xb, rowBase, colBase, s + 2, side, srow, skq, curA);
        mfma_stage8(us, 0, wr, wcp, khalf, lrow, acc);
        if (s + 1 <= 24) gr_conv(us, BUF_STRIDE, curB, side, srow, skq, rs);
        if (s + 1 <= 24) {
            asm volatile("s_waitcnt lgkmcnt(0)" ::: "memory");
            rawbar();
            if (s + 3 <= 24) gr_load(Xb, rowBase, colBase, s + 3, side, srow, skq, curB);
            mfma_stage8(us, BUF_STRIDE, wr, wcp, khalf, lrow, acc);
            gr_conv(us, 0, curA, side, srow, skq, rs);
        }
    }

    {   // means: reduce 4 lanes (skq 0..3) sharing a row; write both panels
        float r0 = rs[0], r1 = rs[1];
        r0 += __shfl_xor(r0, 1, 64); r0 += __shfl_xor(r0, 2, 64);
        r1 += __shfl_xor(r1, 1, 64); r1 += __shfl_xor(r1, 2, 64);
        if ((tid & 3) == 0) {
            int rr = tid >> 2;
            means[bb * CD + rowBase + rr] = r0 * (1.0f / NX);
            means[bb * CD + colBase + rr] = r1 * (1.0f / NX);
        }
    }

    acc_bounce(fsmem, acc, wr, wcp, khalf, lrow);   // syncthreads drains means stores
    const int rloc = tid & 127;
    const int r = rowBase + rloc;
    const float mr = means[bb * CD + r];
    const bool diagblk = (rowBase == colBase);
    float dv = 0.f;
    #pragma unroll
    for (int gi = 0; gi < 4; ++gi) {
        int g = (tid >> 7) + gi * 4;
        int c0 = colBase + g * 8;
        int so = swoff(r, c0);
        float v[8];
        #pragma unroll
        for (int j = 0; j < 8; ++j) {
            v[j] = fsmem[rloc * 129 + g * 8 + j] * (1.0f / NX) - mr * means[bb * CD + c0 + j];
            if (diagblk && (c0 + j) == r) dv += v[j];
        }
        store8(Gh + (size_t)bb * MSZ + so, Gl + (size_t)bb * MSZ + so, v);
    }
    if (diagblk) {
        for (int off = 32; off; off >>= 1) dv += __shfl_down(dv, off, 64);
        if (lane == 0) dsh[wv] = dv;
        __syncthreads();
        if (tid == 0) {
            float s = ((dsh[0] + dsh[1]) + (dsh[2] + dsh[3]))
                    + ((dsh[4] + dsh[5]) + (dsh[6] + dsh[7]));
            atomicAdd(&tr[bb], s);       // agent-scope atomic at coherence point
        }
    }
}

// ---------------------------------------------------------------------------
__device__ __forceinline__ void ns_prefetch(const ushort_t* const* arrp, ushort_t* us,
                                            int wv, int lane, int s, int buf) {
    #pragma unroll
    for (int j = 0; j < 4; ++j) {
        int ck = wv * 4 + j;
        int arr = ck >> 3, rid = (ck >> 1) & 3, half = ck & 1;
        const ushort_t* g = arrp[arr] + s * 4096 + rid * 1024 + half * 512 + lane * 8;
        ushort_t* l = us + buf * BUF_STRIDE + arr * ARR_STRIDE + rid * REG_STRIDE + half * 512;
        __builtin_amdgcn_global_load_lds(
            (const __attribute__((address_space(1))) unsigned int*)g,
            (__attribute__((address_space(3))) unsigned int*)l, 16, 0, 0);
    }
}

// NS GEMM phase (round-5 proven 4-buf counted-vmcnt loop).
// ROUND-9/10 NaN ROOT CAUSE fixed here: the entry __syncthreads. Without it,
// a fast wave entering this phase issues global_load_lds DMA into fsmem
// buf0..2 while slower waves of the SAME block are still doing the previous
// phase's epilogue LDS reads from the same region (the G4->G5 boundary had
// no gbar). The entry barrier structurally prevents that race for every
// phase; after a gbar it is nearly free.
// MODE 2: y = 1.5*it*M - 0.5*it^2*acc; O1=y; O2 = 1.5*I - 0.5*y   (Y1,Z1)
// MODE 4: O1 = acc (P=Y1^2); O2 = 2.25*I - 1.5*M + 0.25*acc (W=Z1^2)
// MODE 1: O1 = 1.5*M - 0.5*acc
// MODE 0: O1 = acc
// MODE 3: out_triu = st * (1.5*M - 0.5*acc)
template<int MODE>
__device__ __forceinline__ void ns_phase(float* fsmem, int tile, int bb,
    const ushort_t* __restrict__ Ah, const ushort_t* __restrict__ Al,
    const ushort_t* __restrict__ Bh, const ushort_t* __restrict__ Bl,
    const ushort_t* __restrict__ Mh, const ushort_t* __restrict__ Ml,
    float it, float st,
    ushort_t* __restrict__ O1h, ushort_t* __restrict__ O1l,
    ushort_t* __restrict__ O2h, ushort_t* __restrict__ O2l,
    float* __restrict__ outT) {
    const int rowBase = (tile >> 1) * 128, colBase = (tile & 1) * 128;
    if (MODE == 3 && rowBase > colBase) return;   // block-uniform; last phase only
    __syncthreads();                               // fence prev phase's LDS reads
    ushort_t* us = (ushort_t*)fsmem;
    const size_t mb = (size_t)bb * MSZ;
    const int tid = threadIdx.x, lane = tid & 63, wv = tid >> 6;
    const int wr = wv >> 1, wcp = wv & 1;
    const int khalf = lane >> 5, lrow = lane & 31;
    const ushort_t* arrp[4] = {
        Ah + mb + (size_t)(rowBase >> 7) * 32768,
        Al + mb + (size_t)(rowBase >> 7) * 32768,
        Bh + mb + (size_t)(colBase >> 7) * 32768,
        Bl + mb + (size_t)(colBase >> 7) * 32768 };

    floatx16 acc[2];
    #pragma unroll
    for (int cq = 0; cq < 2; ++cq)
        #pragma unroll
        for (int i = 0; i < 16; ++i) acc[cq][i] = 0.f;

    ns_prefetch(arrp, us, wv, lane, 0, 0);
    ns_prefetch(arrp, us, wv, lane, 1, 1);
    ns_prefetch(arrp, us, wv, lane, 2, 2);
    #pragma unroll
    for (int s = 0; s < 8; ++s) {
        if (s <= 5)      asm volatile("s_waitcnt vmcnt(8)" ::: "memory");
        else if (s == 6) asm volatile("s_waitcnt vmcnt(4)" ::: "memory");
        else             asm volatile("s_waitcnt vmcnt(0)" ::: "memory");
        rawbar();
        mfma_stage8(us, (s & 3) * BUF_STRIDE, wr, wcp, khalf, lrow, acc);
        if (s < 5) ns_prefetch(arrp, us, wv, lane, s + 3, (s + 3) & 3);
    }

    acc_bounce(fsmem, acc, wr, wcp, khalf, lrow);
    const int rloc = tid & 127;
    const int r = rowBase + rloc;
    #pragma unroll
    for (int gi = 0; gi < 4; ++gi) {
        int g = (tid >> 7) + gi * 4;
        int c0 = colBase + g * 8;
        int so = swoff(r, c0);
        float v[8];
        #pragma unroll
        for (int j = 0; j < 8; ++j) v[j] = fsmem[rloc * 129 + g * 8 + j];
        if (MODE == 0) {
            store8(O1h + mb + so, O1l + mb + so, v);
        } else {
            float mv[8];
            {
                uint4 mh4 = *(const uint4*)(Mh + mb + so);
                uint4 ml4 = *(const uint4*)(Ml + mb + so);
                const uint_t mhw[4] = {mh4.x, mh4.y, mh4.z, mh4.w};
                const uint_t mlw[4] = {ml4.x, ml4.y, ml4.z, ml4.w};
                #pragma unroll
                for (int i = 0; i < 4; ++i) {
                    mv[2*i]   = __uint_as_float(mhw[i] << 16) + __uint_as_float(mlw[i] << 16);
                    mv[2*i+1] = __uint_as_float(mhw[i] & 0xffff0000u) + __uint_as_float(mlw[i] & 0xffff0000u);
                }
            }
            if (MODE == 1) {
                float y[8];
                #pragma unroll
                for (int j = 0; j < 8; ++j) y[j] = fmaf(1.5f, mv[j], -0.5f * v[j]);
                store8(O1h + mb + so, O1l + mb + so, y);
            } else if (MODE == 2) {
                float y[8], z[8];
                #pragma unroll
                for (int j = 0; j < 8; ++j) {
                    y[j] = 1.5f * it * mv[j] - 0.5f * it * it * v[j];
                    z[j] = ((r == c0 + j) ? 1.5f : 0.f) - 0.5f * y[j];
                }
                store8(O1h + mb + so, O1l + mb + so, y);
                store8(O2h + mb + so, O2l + mb + so, z);
            } else if (MODE == 4) {
                float w[8];
                #pragma unroll
                for (int j = 0; j < 8; ++j)
                    w[j] = ((r == c0 + j) ? 2.25f : 0.f) - 1.5f * mv[j] + 0.25f * v[j];
                store8(O1h + mb + so, O1l + mb + so, v);   // P = acc
                store8(O2h + mb + so, O2l + mb + so, w);   // W = Z1^2
            } else {   // MODE 3
                int tb = r * CD - (r * (r - 1)) / 2 - r;
                #pragma unroll
                for (int j = 0; j < 8; ++j) {
                    float y = fmaf(1.5f, mv[j], -0.5f * v[j]);
                    int c = c0 + j;
                    if (c >= r) outT[(size_t)bb * TRIU_N + tb + c] = st * y;
                }
            }
        }
    }
}

// ---------------------------------------------------------------------------
// Full chain, one persistent kernel, per-batch barriers:
//   gram -> b0 -> G1(Y1,Z1) -> b1 -> G2(P,W) -> b2 -> G3(Y2) -> b3 ->
//   G4(Z2); G5(R) [global bufs disjoint; LDS race fenced by ns_phase's
//   entry __syncthreads] -> b4 -> G6(out)
__global__ __launch_bounds__(512, 1)
void fused_all(const float* __restrict__ X,
               ushort_t* __restrict__ S0h, ushort_t* __restrict__ S0l,
               ushort_t* __restrict__ S1h, ushort_t* __restrict__ S1l,
               ushort_t* __restrict__ S2h, ushort_t* __restrict__ S2l,
               ushort_t* __restrict__ S3h, ushort_t* __restrict__ S3l,
               ushort_t* __restrict__ S4h, ushort_t* __restrict__ S4l,
               float* __restrict__ means, float* __restrict__ tr,
               float* __restrict__ outT, unsigned* __restrict__ bars) {
    __shared__ __align__(16) float fsmem[33024];   // 132 KB
    int tile, bb;
    decode_bid(blockIdx.x, tile, bb);

    gram_phase(fsmem, X, means, tr, S0h, S0l, tile, bb);
    gbar(bars, bb * 8 + 0);

    const float trv = tr[bb];                      // fresh post-acquire
    const float it = 1.0f / trv, st = sqrtf(trv);

    // G1: Y1 -> S1, Z1 -> S2
    ns_phase<2>(fsmem, tile, bb, S0h, S0l, S0h, S0l, S0h, S0l, it, 0.f,
                S1h, S1l, S2h, S2l, nullptr);
    gbar(bars, bb * 8 + 1);
    // G2: P -> S3, W -> S0
    ns_phase<4>(fsmem, tile, bb, S1h, S1l, S1h, S1l, S1h, S1l, 0.f, 0.f,
                S3h, S3l, S0h, S0l, nullptr);
    gbar(bars, bb * 8 + 2);
    // G3: Y2 = 1.5*Y1 - 0.5*Z1*P -> S4
    ns_phase<1>(fsmem, tile, bb, S2h, S2l, S3h, S3l, S1h, S1l, 0.f, 0.f,
                S4h, S4l, nullptr, nullptr, nullptr);
    gbar(bars, bb * 8 + 3);
    // G4: Z2 = 1.5*Z1 - 0.5*W*Y2 -> S1
    ns_phase<1>(fsmem, tile, bb, S0h, S0l, S4h, S4l, S2h, S2l, 0.f, 0.f,
                S1h, S1l, nullptr, nullptr, nullptr);
    // G5: R = Y2^2 -> S3
    ns_phase<0>(fsmem, tile, bb, S4h, S4l, S4h, S4l, nullptr, nullptr, 0.f, 0.f,
                S3h, S3l, nullptr, nullptr, nullptr);
    gbar(bars, bb * 8 + 4);
    // G6: out = st * (1.5*Y2 - 0.5*Z2*R), triu-packed
    ns_phase<3>(fsmem, tile, bb, S1h, S1l, S3h, S3l, S4h, S4l, 0.f, st,
                nullptr, nullptr, nullptr, nullptr, outT);
}

// ---------------------------------------------------------------------------
extern "C" void kernel_launch(void* const* d_in, const int* in_sizes, int n_in,
                              void* d_out, int out_size, void* d_ws, size_t ws_size,
                              hipStream_t stream) {
    const float* x = (const float*)d_in[0];
    float* out = (float*)d_out;
    char* ws = (char*)d_ws;
    const size_t HS = (size_t)BATCH * MSZ * 2;   // bytes per matrix array (8 MB)
    ushort_t* S0h = (ushort_t*)(ws + 0 * HS);
    ushort_t* S0l = (ushort_t*)(ws + 1 * HS);
    ushort_t* S1h = (ushort_t*)(ws + 2 * HS);
    ushort_t* S1l = (ushort_t*)(ws + 3 * HS);
    ushort_t* S2h = (ushort_t*)(ws + 4 * HS);
    ushort_t* S2l = (ushort_t*)(ws + 5 * HS);
    ushort_t* S3h = (ushort_t*)(ws + 6 * HS);
    ushort_t* S3l = (ushort_t*)(ws + 7 * HS);
    ushort_t* S4h = (ushort_t*)(ws + 8 * HS);
    ushort_t* S4l = (ushort_t*)(ws + 9 * HS);
    float* means = (float*)(ws + 10 * HS);
    float* tr = means + BATCH * CD;
    unsigned* bars = (unsigned*)(tr + BATCH);

    // zero tr (64 floats) + bars (64*8 uints) in one captured memset
    hipMemsetAsync(tr, 0, BATCH * sizeof(float) + BATCH * 8 * sizeof(unsigned), stream);
    fused_all<<<256, 512, 0, stream>>>(x, S0h, S0l, S1h, S1l, S2h, S2l,
                                       S3h, S3l, S4h, S4l, means, tr, out, bars);
}

// Round 12
// 213.969 us; speedup vs baseline: 1.0296x; 1.0296x over previous
//
#include <hip/hip_runtime.h>
#include <math.h>

#define BATCH 64
#define CD 256
#define NX 784
#define TRIU_N 32896
#define MSZ 65536           // elems per swizzled 256x256 matrix
#define REG_STRIDE 1032     // 128 rows * 8 elems + 8 pad (bank-conflict break)
#define ARR_STRIDE 4128     // 4 regions
#define BUF_STRIDE 16512    // 4 arrays (Ahi,Alo,Bhi,Blo) = 33KB per stage buffer

typedef unsigned short ushort_t;
typedef unsigned int uint_t;
typedef __attribute__((ext_vector_type(8))) short short8;
typedef __attribute__((ext_vector_type(16))) float floatx16;

// XCD co-location (perf heuristic only; correctness is mapping-independent).
__device__ __forceinline__ void decode_bid(int bid, int& tile, int& bb) {
    int xcd = bid & 7, g = bid >> 3;
    tile = g & 3;
    bb = ((g >> 2) << 3) | xcd;
}

__device__ __forceinline__ float bf2f(ushort_t h) {
    return __uint_as_float(((uint_t)h) << 16);
}
__device__ __forceinline__ void pack2(float f0, float f1, uint_t& hp, uint_t& lp) {
    uint_t h, l;
    asm("v_cvt_pk_bf16_f32 %0, %1, %2" : "=v"(h) : "v"(f0), "v"(f1));
    float r0 = f0 - __uint_as_float(h << 16);
    float r1 = f1 - __uint_as_float(h & 0xffff0000u);
    asm("v_cvt_pk_bf16_f32 %0, %1, %2" : "=v"(l) : "v"(r0), "v"(r1));
    hp = h; lp = l;
}
// Plain compiler-tracked stores only (round-9/10 lesson: asm stores are
// invisible to waitcnt insertion and the memory legalizer).
__device__ __forceinline__ void store8(ushort_t* H, ushort_t* L, const float* y) {
    uint_t hw[4], lw[4];
    #pragma unroll
    for (int i = 0; i < 4; ++i) pack2(y[2*i], y[2*i+1], hw[i], lw[i]);
    *(uint4*)H = make_uint4(hw[0], hw[1], hw[2], hw[3]);
    *(uint4*)L = make_uint4(lw[0], lw[1], lw[2], lw[3]);
}

// swizzled offset of element (r,c) within one 256x256 matrix
__device__ __forceinline__ int swoff(int r, int c) {
    int p = r >> 7, s = (c >> 5) & 7, ks = (c >> 4) & 1, kh = (c >> 3) & 1;
    return ((((p * 8 + s) * 2 + ks) * 2 + kh) * 128 + (r & 127)) * 8 + (c & 7);
}

// raw workgroup barrier (no compiler vmcnt(0) drain); caller must wait first.
__device__ __forceinline__ void rawbar() {
    __builtin_amdgcn_s_barrier();
    __builtin_amdgcn_sched_barrier(0);
}

// Per-batch device barrier (4 participant blocks) -- byte-identical to the
// round-11 PASSING version. Producer: __syncthreads drains tracked stores,
// tid0 publishes with RELEASE RMW (legalizer emits waitcnt + buffer_wbl2).
// Consumer: relaxed poll + ACQUIRE fence (buffer_inv). Monotonic counters,
// memset per launch. All 256 blocks co-resident (1 block/CU) -> no deadlock.
__device__ __forceinline__ void gbar(unsigned* bars, int slot) {
    __syncthreads();
    if (threadIdx.x == 0) {
        __hip_atomic_fetch_add(&bars[slot], 1u, __ATOMIC_RELEASE, __HIP_MEMORY_SCOPE_AGENT);
        while (__hip_atomic_load(&bars[slot], __ATOMIC_RELAXED, __HIP_MEMORY_SCOPE_AGENT) < 4u)
            __builtin_amdgcn_s_sleep(4);
        __builtin_amdgcn_fence(__ATOMIC_ACQUIRE, "agent");
    }
    __syncthreads();
    __builtin_amdgcn_sched_barrier(0);
}

// ---------------------------------------------------------------------------
// One BK=32 stage from LDS: wave computes 2 quadrants (wr, wcp*2+{0,1}).
__device__ __forceinline__ void mfma_stage8(const ushort_t* us, int bufbase,
                                            int wr, int wcp, int khalf, int lrow,
                                            floatx16* acc) {
    __builtin_amdgcn_s_setprio(1);
    #pragma unroll
    for (int ks = 0; ks < 2; ++ks) {
        const int rid = ks * 2 + khalf;
        const ushort_t* rb = us + bufbase + rid * REG_STRIDE + lrow * 8;
        short8 aH = *(const short8*)(rb + wr * 256);
        short8 aL = *(const short8*)(rb + ARR_STRIDE + wr * 256);
        #pragma unroll
        for (int cq = 0; cq < 2; ++cq) {
            const int col = wcp * 2 + cq;
            short8 bH = *(const short8*)(rb + 2 * ARR_STRIDE + col * 256);
            short8 bL = *(const short8*)(rb + 3 * ARR_STRIDE + col * 256);
            acc[cq] = __builtin_amdgcn_mfma_f32_32x32x16_bf16(aH, bH, acc[cq], 0, 0, 0);
            acc[cq] = __builtin_amdgcn_mfma_f32_32x32x16_bf16(aH, bL, acc[cq], 0, 0, 0);
            acc[cq] = __builtin_amdgcn_mfma_f32_32x32x16_bf16(aL, bH, acc[cq], 0, 0, 0);
        }
    }
    __builtin_amdgcn_s_setprio(0);
}

// accumulator -> fsmem bounce (stride 129 -> conflict-free)
__device__ __forceinline__ void acc_bounce(float* fsmem, const floatx16* acc,
                                           int wr, int wcp, int khalf, int lrow) {
    __syncthreads();
    #pragma unroll
    for (int cq = 0; cq < 2; ++cq)
        #pragma unroll
        for (int i = 0; i < 16; ++i) {
            int rl = (i & 3) + ((i >> 2) << 3) + (khalf << 2);
            fsmem[(wr * 32 + rl) * 129 + (wcp * 2 + cq) * 32 + lrow] = acc[cq][i];
        }
    __syncthreads();
}

// ---------------------------------------------------------------------------
// Gram helpers: named-register double buffer (static indexing, rule #20)
struct Cur { float4 v[2][2]; };

__device__ __forceinline__ void gr_load(const float* Xb, int rowBase, int colBase, int s,
                                        const int* side, const int* srow, const int* skq,
                                        Cur& c) {
    #pragma unroll
    for (int q = 0; q < 2; ++q) {
        int gk = s * 32 + skq[q] * 8;
        if (gk < NX) {
            const float* p = Xb + (size_t)((side[q] ? colBase : rowBase) + srow[q]) * NX + gk;
            c.v[q][0] = *(const float4*)p;
            c.v[q][1] = *(const float4*)(p + 4);
        } else {
            c.v[q][0] = make_float4(0.f, 0.f, 0.f, 0.f);
            c.v[q][1] = make_float4(0.f, 0.f, 0.f, 0.f);
        }
    }
}

__device__ __forceinline__ void gr_conv(ushort_t* us, int bufbase, const Cur& c,
                                        const int* side, const int* srow, const int* skq,
                                        float* rs) {
    #pragma unroll
    for (int q = 0; q < 2; ++q) {
        float f[8] = {c.v[q][0].x, c.v[q][0].y, c.v[q][0].z, c.v[q][0].w,
                      c.v[q][1].x, c.v[q][1].y, c.v[q][1].z, c.v[q][1].w};
        rs[q] += ((f[0] + f[1]) + (f[2] + f[3])) + ((f[4] + f[5]) + (f[6] + f[7]));
        uint_t hp[4], lp[4];
        #pragma unroll
        for (int i = 0; i < 4; ++i) pack2(f[2*i], f[2*i+1], hp[i], lp[i]);
        int base = bufbase + (side[q] * 2) * ARR_STRIDE + skq[q] * REG_STRIDE + srow[q] * 8;
        *(uint4*)(us + base)              = make_uint4(hp[0], hp[1], hp[2], hp[3]);
        *(uint4*)(us + base + ARR_STRIDE) = make_uint4(lp[0], lp[1], lp[2], lp[3]);
    }
}

// ---------------------------------------------------------------------------
// Gram phase (round-11 proven): Sigma = X X^T/n - m m^T, means + trace fused.
__device__ __forceinline__ void gram_phase(float* fsmem, const float* __restrict__ X,
                                           float* __restrict__ means, float* __restrict__ tr,
                                           ushort_t* __restrict__ Gh, ushort_t* __restrict__ Gl,
                                           int tile, int bb) {
    ushort_t* us = (ushort_t*)fsmem;
    float* dsh = fsmem + 16512;            // scratch beyond gram's 66KB window
    const int rowBase = (tile >> 1) * 128, colBase = (tile & 1) * 128;
    const int tid = threadIdx.x, lane = tid & 63, wv = tid >> 6;
    const int wr = wv >> 1, wcp = wv & 1;
    const int khalf = lane >> 5, lrow = lane & 31;
    const float* Xb = X + (size_t)bb * CD * NX;

    floatx16 acc[2];
    #pragma unroll
    for (int cq = 0; cq < 2; ++cq)
        #pragma unroll
        for (int i = 0; i < 16; ++i) acc[cq][i] = 0.f;

    int side[2], srow[2], skq[2];
    #pragma unroll
    for (int q = 0; q < 2; ++q) {
        int gid = q * 512 + tid;
        side[q] = gid >> 9;
        srow[q] = (gid >> 2) & 127;
        skq[q]  = gid & 3;
    }
    float rs[2] = {0.f, 0.f};

    Cur curA, curB;
    gr_load(Xb, rowBase, colBase, 0, side, srow, skq, curA);
    gr_load(Xb, rowBase, colBase, 1, side, srow, skq, curB);
    gr_conv(us, 0, curA, side, srow, skq, rs);          // stage 0 -> buf0

    for (int s = 0; s < 25; s += 2) {
        asm volatile("s_waitcnt lgkmcnt(0)" ::: "memory");
        rawbar();
        if (s + 2 <= 24) gr_load(Xb, rowBase, colBase, s + 2, side, srow, skq, curA);
        mfma_stage8(us, 0, wr, wcp, khalf, lrow, acc);
        if (s + 1 <= 24) gr_conv(us, BUF_STRIDE, curB, side, srow, skq, rs);
        if (s + 1 <= 24) {
            asm volatile("s_waitcnt lgkmcnt(0)" ::: "memory");
            rawbar();
            if (s + 3 <= 24) gr_load(Xb, rowBase, colBase, s + 3, side, srow, skq, curB);
            mfma_stage8(us, BUF_STRIDE, wr, wcp, khalf, lrow, acc);
            gr_conv(us, 0, curA, side, srow, skq, rs);
        }
    }

    {   // means: reduce 4 lanes (skq 0..3) sharing a row; write both panels
        float r0 = rs[0], r1 = rs[1];
        r0 += __shfl_xor(r0, 1, 64); r0 += __shfl_xor(r0, 2, 64);
        r1 += __shfl_xor(r1, 1, 64); r1 += __shfl_xor(r1, 2, 64);
        if ((tid & 3) == 0) {
            int rr = tid >> 2;
            means[bb * CD + rowBase + rr] = r0 * (1.0f / NX);
            means[bb * CD + colBase + rr] = r1 * (1.0f / NX);
        }
    }

    acc_bounce(fsmem, acc, wr, wcp, khalf, lrow);   // syncthreads drains means stores
    const int rloc = tid & 127;
    const int r = rowBase + rloc;
    const float mr = means[bb * CD + r];
    const bool diagblk = (rowBase == colBase);
    float dv = 0.f;
    #pragma unroll
    for (int gi = 0; gi < 4; ++gi) {
        int g = (tid >> 7) + gi * 4;
        int c0 = colBase + g * 8;
        int so = swoff(r, c0);
        float v[8];
        #pragma unroll
        for (int j = 0; j < 8; ++j) {
            v[j] = fsmem[rloc * 129 + g * 8 + j] * (1.0f / NX) - mr * means[bb * CD + c0 + j];
            if (diagblk && (c0 + j) == r) dv += v[j];
        }
        store8(Gh + (size_t)bb * MSZ + so, Gl + (size_t)bb * MSZ + so, v);
    }
    if (diagblk) {
        for (int off = 32; off; off >>= 1) dv += __shfl_down(dv, off, 64);
        if (lane == 0) dsh[wv] = dv;
        __syncthreads();
        if (tid == 0) {
            float s = ((dsh[0] + dsh[1]) + (dsh[2] + dsh[3]))
                    + ((dsh[4] + dsh[5]) + (dsh[6] + dsh[7]));
            atomicAdd(&tr[bb], s);
        }
    }
}

// ---------------------------------------------------------------------------
__device__ __forceinline__ void ns_prefetch(const ushort_t* const* arrp, ushort_t* us,
                                            int wv, int lane, int s, int buf) {
    #pragma unroll
    for (int j = 0; j < 4; ++j) {
        int ck = wv * 4 + j;
        int arr = ck >> 3, rid = (ck >> 1) & 3, half = ck & 1;
        const ushort_t* g = arrp[arr] + s * 4096 + rid * 1024 + half * 512 + lane * 8;
        ushort_t* l = us + buf * BUF_STRIDE + arr * ARR_STRIDE + rid * REG_STRIDE + half * 512;
        __builtin_amdgcn_global_load_lds(
            (const __attribute__((address_space(1))) unsigned int*)g,
            (__attribute__((address_space(3))) unsigned int*)l, 16, 0, 0);
    }
}

// NS GEMM phase (round-11 proven, incl. the entry __syncthreads that fences
// the previous phase's LDS reads against this phase's DMA writes).
// MODE 2: y = 1.5*it*M - 0.5*it^2*acc; O1=y; O2 = 1.5*I - 0.5*y   (Y1,Z1)
// MODE 4: O1 = acc (P=Y1^2); O2 = 2.25*I - 1.5*M + 0.25*acc (W=Z1^2)
// MODE 1: O1 = 1.5*M - 0.5*acc
// MODE 0: O1 = acc
// MODE 3: out_triu = st * (1.5*M - 0.5*acc)
template<int MODE>
__device__ __forceinline__ void ns_phase(float* fsmem, int tile, int bb,
    const ushort_t* __restrict__ Ah, const ushort_t* __restrict__ Al,
    const ushort_t* __restrict__ Bh, const ushort_t* __restrict__ Bl,
    const ushort_t* __restrict__ Mh, const ushort_t* __restrict__ Ml,
    float it, float st,
    ushort_t* __restrict__ O1h, ushort_t* __restrict__ O1l,
    ushort_t* __restrict__ O2h, ushort_t* __restrict__ O2l,
    float* __restrict__ outT) {
    const int rowBase = (tile >> 1) * 128, colBase = (tile & 1) * 128;
    if (MODE == 3 && rowBase > colBase) return;   // block-uniform; last phase only
    __syncthreads();                               // fence prev phase's LDS reads
    ushort_t* us = (ushort_t*)fsmem;
    const size_t mb = (size_t)bb * MSZ;
    const int tid = threadIdx.x, lane = tid & 63, wv = tid >> 6;
    const int wr = wv >> 1, wcp = wv & 1;
    const int khalf = lane >> 5, lrow = lane & 31;
    const ushort_t* arrp[4] = {
        Ah + mb + (size_t)(rowBase >> 7) * 32768,
        Al + mb + (size_t)(rowBase >> 7) * 32768,
        Bh + mb + (size_t)(colBase >> 7) * 32768,
        Bl + mb + (size_t)(colBase >> 7) * 32768 };

    floatx16 acc[2];
    #pragma unroll
    for (int cq = 0; cq < 2; ++cq)
        #pragma unroll
        for (int i = 0; i < 16; ++i) acc[cq][i] = 0.f;

    ns_prefetch(arrp, us, wv, lane, 0, 0);
    ns_prefetch(arrp, us, wv, lane, 1, 1);
    ns_prefetch(arrp, us, wv, lane, 2, 2);
    #pragma unroll
    for (int s = 0; s < 8; ++s) {
        if (s <= 5)      asm volatile("s_waitcnt vmcnt(8)" ::: "memory");
        else if (s == 6) asm volatile("s_waitcnt vmcnt(4)" ::: "memory");
        else             asm volatile("s_waitcnt vmcnt(0)" ::: "memory");
        rawbar();
        mfma_stage8(us, (s & 3) * BUF_STRIDE, wr, wcp, khalf, lrow, acc);
        if (s < 5) ns_prefetch(arrp, us, wv, lane, s + 3, (s + 3) & 3);
    }

    acc_bounce(fsmem, acc, wr, wcp, khalf, lrow);
    const int rloc = tid & 127;
    const int r = rowBase + rloc;
    #pragma unroll
    for (int gi = 0; gi < 4; ++gi) {
        int g = (tid >> 7) + gi * 4;
        int c0 = colBase + g * 8;
        int so = swoff(r, c0);
        float v[8];
        #pragma unroll
        for (int j = 0; j < 8; ++j) v[j] = fsmem[rloc * 129 + g * 8 + j];
        if (MODE == 0) {
            store8(O1h + mb + so, O1l + mb + so, v);
        } else {
            float mv[8];
            {
                uint4 mh4 = *(const uint4*)(Mh + mb + so);
                uint4 ml4 = *(const uint4*)(Ml + mb + so);
                const uint_t mhw[4] = {mh4.x, mh4.y, mh4.z, mh4.w};
                const uint_t mlw[4] = {ml4.x, ml4.y, ml4.z, ml4.w};
                #pragma unroll
                for (int i = 0; i < 4; ++i) {
                    mv[2*i]   = __uint_as_float(mhw[i] << 16) + __uint_as_float(mlw[i] << 16);
                    mv[2*i+1] = __uint_as_float(mhw[i] & 0xffff0000u) + __uint_as_float(mlw[i] & 0xffff0000u);
                }
            }
            if (MODE == 1) {
                float y[8];
                #pragma unroll
                for (int j = 0; j < 8; ++j) y[j] = fmaf(1.5f, mv[j], -0.5f * v[j]);
                store8(O1h + mb + so, O1l + mb + so, y);
            } else if (MODE == 2) {
                float y[8], z[8];
                #pragma unroll
                for (int j = 0; j < 8; ++j) {
                    y[j] = 1.5f * it * mv[j] - 0.5f * it * it * v[j];
                    z[j] = ((r == c0 + j) ? 1.5f : 0.f) - 0.5f * y[j];
                }
                store8(O1h + mb + so, O1l + mb + so, y);
                store8(O2h + mb + so, O2l + mb + so, z);
            } else if (MODE == 4) {
                float w[8];
                #pragma unroll
                for (int j = 0; j < 8; ++j)
                    w[j] = ((r == c0 + j) ? 2.25f : 0.f) - 1.5f * mv[j] + 0.25f * v[j];
                store8(O1h + mb + so, O1l + mb + so, v);   // P = acc
                store8(O2h + mb + so, O2l + mb + so, w);   // W = Z1^2
            } else {   // MODE 3
                int tb = r * CD - (r * (r - 1)) / 2 - r;
                #pragma unroll
                for (int j = 0; j < 8; ++j) {
                    float y = fmaf(1.5f, mv[j], -0.5f * v[j]);
                    int c = c0 + j;
                    if (c >= r) outT[(size_t)bb * TRIU_N + tb + c] = st * y;
                }
            }
        }
    }
}

// ---------------------------------------------------------------------------
// 4-kernel grouping: 2 phases per kernel, ONE in-kernel per-batch barrier in
// K1/K2, none in K3/K4 (G4;G5 need no barrier -- r11 proven; K-boundaries
// provide full coherence for the rest).
__global__ __launch_bounds__(512, 1)
void fused_k1(const float* __restrict__ X,
              ushort_t* __restrict__ S0h, ushort_t* __restrict__ S0l,
              ushort_t* __restrict__ S1h, ushort_t* __restrict__ S1l,
              ushort_t* __restrict__ S2h, ushort_t* __restrict__ S2l,
              float* __restrict__ means, float* __restrict__ tr,
              unsigned* __restrict__ bars) {
    __shared__ __align__(16) float fsmem[33024];   // 132 KB
    int tile, bb;
    decode_bid(blockIdx.x, tile, bb);
    gram_phase(fsmem, X, means, tr, S0h, S0l, tile, bb);   // Sigma -> S0
    gbar(bars, bb * 2 + 0);
    const float it = 1.0f / tr[bb];
    // G1: Y1 -> S1, Z1 -> S2
    ns_phase<2>(fsmem, tile, bb, S0h, S0l, S0h, S0l, S0h, S0l, it, 0.f,
                S1h, S1l, S2h, S2l, nullptr);
}

__global__ __launch_bounds__(512, 1)
void fused_k2(const ushort_t* __restrict__ S1h, const ushort_t* __restrict__ S1l,
              const ushort_t* __restrict__ S2h, const ushort_t* __restrict__ S2l,
              ushort_t* __restrict__ S3h, ushort_t* __restrict__ S3l,
              ushort_t* __restrict__ S0h, ushort_t* __restrict__ S0l,
              ushort_t* __restrict__ S4h, ushort_t* __restrict__ S4l,
              unsigned* __restrict__ bars) {
    __shared__ __align__(16) float fsmem[33024];
    int tile, bb;
    decode_bid(blockIdx.x, tile, bb);
    // G2: P -> S3, W -> S0  (A=B=M=Y1)
    ns_phase<4>(fsmem, tile, bb, S1h, S1l, S1h, S1l, S1h, S1l, 0.f, 0.f,
                S3h, S3l, S0h, S0l, nullptr);
    gbar(bars, bb * 2 + 1);
    // G3: Y2 = 1.5*Y1 - 0.5*Z1*P -> S4
    ns_phase<1>(fsmem, tile, bb, S2h, S2l, S3h, S3l, S1h, S1l, 0.f, 0.f,
                S4h, S4l, nullptr, nullptr, nullptr);
}

__global__ __launch_bounds__(512, 1)
void fused_k3(const ushort_t* __restrict__ S0h, const ushort_t* __restrict__ S0l,
              const ushort_t* __restrict__ S4h, const ushort_t* __restrict__ S4l,
              const ushort_t* __restrict__ S2h, const ushort_t* __restrict__ S2l,
              ushort_t* __restrict__ S1h, ushort_t* __restrict__ S1l,
              ushort_t* __restrict__ S3h, ushort_t* __restrict__ S3l) {
    __shared__ __align__(16) float fsmem[33024];
    int tile, bb;
    decode_bid(blockIdx.x, tile, bb);
    // G4: Z2 = 1.5*Z1 - 0.5*W*Y2 -> S1
    ns_phase<1>(fsmem, tile, bb, S0h, S0l, S4h, S4l, S2h, S2l, 0.f, 0.f,
                S1h, S1l, nullptr, nullptr, nullptr);
    // G5: R = Y2^2 -> S3 (disjoint buffers; LDS race fenced by entry sync)
    ns_phase<0>(fsmem, tile, bb, S4h, S4l, S4h, S4l, nullptr, nullptr, 0.f, 0.f,
                S3h, S3l, nullptr, nullptr, nullptr);
}

__global__ __launch_bounds__(512, 1)
void fused_k4(const ushort_t* __restrict__ S1h, const ushort_t* __restrict__ S1l,
              const ushort_t* __restrict__ S3h, const ushort_t* __restrict__ S3l,
              const ushort_t* __restrict__ S4h, const ushort_t* __restrict__ S4l,
              const float* __restrict__ tr, float* __restrict__ outT) {
    __shared__ __align__(16) float fsmem[33024];
    int tile, bb;
    decode_bid(blockIdx.x, tile, bb);
    const float st = sqrtf(tr[bb]);
    // G6: out = st * (1.5*Y2 - 0.5*Z2*R), triu-packed
    ns_phase<3>(fsmem, tile, bb, S1h, S1l, S3h, S3l, S4h, S4l, 0.f, st,
                nullptr, nullptr, nullptr, nullptr, outT);
}

// ---------------------------------------------------------------------------
extern "C" void kernel_launch(void* const* d_in, const int* in_sizes, int n_in,
                              void* d_out, int out_size, void* d_ws, size_t ws_size,
                              hipStream_t stream) {
    const float* x = (const float*)d_in[0];
    float* out = (float*)d_out;
    char* ws = (char*)d_ws;
    const size_t HS = (size_t)BATCH * MSZ * 2;   // bytes per matrix array (8 MB)
    ushort_t* S0h = (ushort_t*)(ws + 0 * HS);
    ushort_t* S0l = (ushort_t*)(ws + 1 * HS);
    ushort_t* S1h = (ushort_t*)(ws + 2 * HS);
    ushort_t* S1l = (ushort_t*)(ws + 3 * HS);
    ushort_t* S2h = (ushort_t*)(ws + 4 * HS);
    ushort_t* S2l = (ushort_t*)(ws + 5 * HS);
    ushort_t* S3h = (ushort_t*)(ws + 6 * HS);
    ushort_t* S3l = (ushort_t*)(ws + 7 * HS);
    ushort_t* S4h = (ushort_t*)(ws + 8 * HS);
    ushort_t* S4l = (ushort_t*)(ws + 9 * HS);
    float* means = (float*)(ws + 10 * HS);
    float* tr = means + BATCH * CD;
    unsigned* bars = (unsigned*)(tr + BATCH);

    // zero tr (64 floats) + bars (64*2 uints) in one captured memset
    hipMemsetAsync(tr, 0, BATCH * sizeof(float) + BATCH * 2 * sizeof(unsigned), stream);
    fused_k1<<<256, 512, 0, stream>>>(x, S0h, S0l, S1h, S1l, S2h, S2l, means, tr, bars);
    fused_k2<<<256, 512, 0, stream>>>(S1h, S1l, S2h, S2l, S3h, S3l, S0h, S0l, S4h, S4l, bars);
    fused_k3<<<256, 512, 0, stream>>>(S0h, S0l, S4h, S4l, S2h, S2l, S1h, S1l, S3h, S3l);
    fused_k4<<<256, 512, 0, stream>>>(S1h, S1l, S3h, S3l, S4h, S4l, tr, out);
}